// Round 4
// baseline (3956.727 us; speedup 1.0000x reference)
//
#include <hip/hip_runtime.h>

// B=64, S=512, I=256, O=256 fp32 LSTM.
// out = [h_seq (64*512*256)] [hT (64*256)] [cT (64*256)]
//
// Phase A: xg = x @ Wx^T + bx + bh  (fp32 LDS-tiled GEMM, known-good)
// Phase B (MFMA scan): 16 blocks x 4 batches, 512 threads = 8 waves (2/SIMD).
//   Wave w owns p in [w*32,w*32+32) x 4 gates = 128 rows of Wh as 64 fp16
//   A-fragments (256 regs -> AGPRs; MFMA reads A from AGPR directly).
//   Per step: B-frags = h(t-1) fp16 from LDS (masked: only lanes b<4 read),
//   64x mfma_f32_16x16x32_f16 -> D[p x b], masked write of y to LDS, barrier,
//   DENSE gate phase (every thread 2 c-updates; transcendentals issue per-wave
//   so density matters), h -> fp16 double-buffered LDS + h_seq store (deferred
//   one barrier to hide vmcnt drain), barrier. 2 barriers/step, no cross-CU
//   communication.

#define SS 512

typedef _Float16 v8h __attribute__((ext_vector_type(8)));
typedef float vf4 __attribute__((ext_vector_type(4)));

__device__ __forceinline__ float sigm(float x) { return 1.f / (1.f + __expf(-x)); }
__device__ __forceinline__ float tanh_f(float x) {
  float e = __expf(-2.f * fabsf(x));
  float r = (1.f - e) / (1.f + e);
  return copysignf(r, x);
}

// ---------------------------------------------------------------- Phase A
__global__ __launch_bounds__(256) void xg_gemm(
    const float* __restrict__ X, const float* __restrict__ W,
    const float* __restrict__ bx, const float* __restrict__ bh,
    float* __restrict__ out)
{
  __shared__ float As[64][68];
  __shared__ float Bs[64][68];
  const int bm = blockIdx.x >> 4;
  const int bn = blockIdx.x & 15;
  const int tid = threadIdx.x;
  const int tn = tid & 15, tm = tid >> 4;
  const int row0 = bm * 64, col0 = bn * 64;
  float acc[4][4] = {};

  for (int k0 = 0; k0 < 256; k0 += 64) {
#pragma unroll
    for (int i = 0; i < 4; i++) {
      const int m = (tid >> 4) + i * 16;
      const int k = (tid & 15) * 4;
      float4 av = *(const float4*)&X[(size_t)(row0 + m) * 256 + k0 + k];
      *(float4*)&As[m][k] = av;
      float4 wv = *(const float4*)&W[(size_t)(col0 + m) * 256 + k0 + k];
      Bs[k + 0][m] = wv.x; Bs[k + 1][m] = wv.y;
      Bs[k + 2][m] = wv.z; Bs[k + 3][m] = wv.w;
    }
    __syncthreads();
#pragma unroll 8
    for (int kk = 0; kk < 64; kk++) {
      const float a0 = As[tm * 4 + 0][kk];
      const float a1 = As[tm * 4 + 1][kk];
      const float a2 = As[tm * 4 + 2][kk];
      const float a3 = As[tm * 4 + 3][kk];
      const float4 bv = *(const float4*)&Bs[kk][tn * 4];
      acc[0][0] = fmaf(a0, bv.x, acc[0][0]); acc[0][1] = fmaf(a0, bv.y, acc[0][1]);
      acc[0][2] = fmaf(a0, bv.z, acc[0][2]); acc[0][3] = fmaf(a0, bv.w, acc[0][3]);
      acc[1][0] = fmaf(a1, bv.x, acc[1][0]); acc[1][1] = fmaf(a1, bv.y, acc[1][1]);
      acc[1][2] = fmaf(a1, bv.z, acc[1][2]); acc[1][3] = fmaf(a1, bv.w, acc[1][3]);
      acc[2][0] = fmaf(a2, bv.x, acc[2][0]); acc[2][1] = fmaf(a2, bv.y, acc[2][1]);
      acc[2][2] = fmaf(a2, bv.z, acc[2][2]); acc[2][3] = fmaf(a2, bv.w, acc[2][3]);
      acc[3][0] = fmaf(a3, bv.x, acc[3][0]); acc[3][1] = fmaf(a3, bv.y, acc[3][1]);
      acc[3][2] = fmaf(a3, bv.z, acc[3][2]); acc[3][3] = fmaf(a3, bv.w, acc[3][3]);
    }
    __syncthreads();
  }

  float bias[4];
#pragma unroll
  for (int j = 0; j < 4; j++) {
    const int col = col0 + tn * 4 + j;
    bias[j] = bx[col] + bh[col];
  }
#pragma unroll
  for (int i = 0; i < 4; i++) {
    float4 o4;
    o4.x = acc[i][0] + bias[0]; o4.y = acc[i][1] + bias[1];
    o4.z = acc[i][2] + bias[2]; o4.w = acc[i][3] + bias[3];
    *(float4*)&out[(size_t)(row0 + tm * 4 + i) * 1024 + col0 + tn * 4] = o4;
  }
}

// ---------------------------------------------------------------- Phase B
__global__ __launch_bounds__(512, 1) void lstm_scan4(
    const float* __restrict__ xg,   // [64][512][1024]
    const float* __restrict__ Wh,   // [1024][256]  row = g*256+p, col = k
    const float* __restrict__ h0,   // [64][256]
    const float* __restrict__ c0,   // [64][256]
    float* __restrict__ out)
{
  // hbuf[par][kfrag8][b][8 halves]: h value k for batch b at [k>>3][b][k&7]
  __shared__ __align__(16) _Float16 hbuf[2][32][16][8];   // 16 KB
  __shared__ __align__(16) float ylds[4][4][256];         // [gate][b][p] 16 KB

  const int tid = threadIdx.x;
  const int bid = blockIdx.x;
  const int w    = tid >> 6;       // wave 0..7
  const int lane = tid & 63;
  const int q    = lane >> 4;      // quad 0..3
  const int l15  = lane & 15;      // MFMA row/col lane index
  const bool bvalid = (l15 < 4);   // batch columns 0..3 are real

  // dense-phase role: thread handles (p = dp, dp+1; batch = db)
  const int db = tid >> 7;               // 0..3
  const int dp = (tid & 127) * 2;        // 0..254 even
  const int gdb = bid * 4 + db;          // global batch, < 64

  // ---- zero hbuf (cols b>=4 never read, but keep deterministic)
  unsigned* hb32 = (unsigned*)&hbuf[0][0][0][0];
  for (int j = tid; j < 4096; j += 512) hb32[j] = 0;
  __syncthreads();

  // ---- stage h0 into hbuf[0]
  {
    float2 hv = *(const float2*)&h0[(size_t)gdb * 256 + dp];
    _Float16 p0 = (_Float16)hv.x, p1 = (_Float16)hv.y;
    unsigned hp = (unsigned)__builtin_bit_cast(unsigned short, p0) |
                  ((unsigned)__builtin_bit_cast(unsigned short, p1) << 16);
    *(unsigned*)&hbuf[0][dp >> 3][db][dp & 7] = hp;
  }

  // ---- A-fragments: A[g][i][kf] = Wh[g*256 + w*32 + i*16 + l15][kf*32 + q*8 + j]
  v8h A[4][2][8];
#pragma unroll
  for (int g = 0; g < 4; ++g)
#pragma unroll
    for (int i = 0; i < 2; ++i)
#pragma unroll
      for (int kf = 0; kf < 8; ++kf) {
        const float* src = Wh + (size_t)(g * 256 + w * 32 + i * 16 + l15) * 256
                              + kf * 32 + q * 8;
        float4 lo = *(const float4*)src;
        float4 hi = *(const float4*)(src + 4);
        v8h a;
        a[0] = (_Float16)lo.x; a[1] = (_Float16)lo.y;
        a[2] = (_Float16)lo.z; a[3] = (_Float16)lo.w;
        a[4] = (_Float16)hi.x; a[5] = (_Float16)hi.y;
        a[6] = (_Float16)hi.z; a[7] = (_Float16)hi.w;
        A[g][i][kf] = a;
      }

  // ---- dense-role persistent state
  float2 cc = *(const float2*)&c0[(size_t)gdb * 256 + dp];
  const float* xgp = xg + (size_t)gdb * SS * 1024 + dp;   // + t*1024 + g*256
  float* hsp = out + (size_t)gdb * SS * 256 + dp;

  float2 xc[4], xn[4];
#pragma unroll
  for (int g = 0; g < 4; ++g) xc[g] = *(const float2*)&xgp[g * 256];

  v8h Bf[8];
#pragma unroll
  for (int kf = 0; kf < 8; ++kf) Bf[kf] = (v8h)(_Float16)0.f;   // zero cols b>=4

  float2 hprev = {0.f, 0.f};
  __syncthreads();

  for (int t = 0; t < SS; ++t) {
    const int par = t & 1, np = par ^ 1;

    // deferred h_seq store for t-1 (drains at barrier1, fully hidden)
    if (t > 0) *(float2*)&hsp[(size_t)(t - 1) * 256] = hprev;

    // ---- B-frags: h(t-1) (masked: only real batch columns)
    if (bvalid) {
#pragma unroll
      for (int kf = 0; kf < 8; ++kf)
        Bf[kf] = *(const v8h*)&hbuf[par][kf * 4 + q][l15][0];
    }

    // ---- prefetch xg(t+1) early (drains at barrier1)
    if (t + 1 < SS) {
      const float* xnp = xgp + (size_t)(t + 1) * 1024;
#pragma unroll
      for (int g = 0; g < 4; ++g) xn[g] = *(const float2*)&xnp[g * 256];
    }

    // ---- MFMA: D[g][i] (p-rows x b-cols)
    vf4 D[4][2];
#pragma unroll
    for (int g = 0; g < 4; ++g)
#pragma unroll
      for (int i = 0; i < 2; ++i) { vf4 z = {0.f, 0.f, 0.f, 0.f}; D[g][i] = z; }
#pragma unroll
    for (int kf = 0; kf < 8; ++kf)
#pragma unroll
      for (int g = 0; g < 4; ++g)
#pragma unroll
        for (int i = 0; i < 2; ++i)
          D[g][i] = __builtin_amdgcn_mfma_f32_16x16x32_f16(
              A[g][i][kf], Bf[kf], D[g][i], 0, 0, 0);

    // ---- scatter y to LDS (masked), compact for dense gate phase
    if (bvalid) {
#pragma unroll
      for (int g = 0; g < 4; ++g)
#pragma unroll
        for (int i = 0; i < 2; ++i)
          *(vf4*)&ylds[g][l15][w * 32 + i * 16 + q * 4] = D[g][i];
    }
    __syncthreads();

    // ---- dense gates: 2 c-updates per thread, all lanes active
    float yf0, yf1, yi0, yi1, yg0, yg1, yo0, yo1;
    {
      float2 pf = *(const float2*)&ylds[0][db][dp];
      float2 pi = *(const float2*)&ylds[1][db][dp];
      float2 pg = *(const float2*)&ylds[2][db][dp];
      float2 po = *(const float2*)&ylds[3][db][dp];
      yf0 = pf.x + xc[0].x; yf1 = pf.y + xc[0].y;
      yi0 = pi.x + xc[1].x; yi1 = pi.y + xc[1].y;
      yg0 = pg.x + xc[2].x; yg1 = pg.y + xc[2].y;
      yo0 = po.x + xc[3].x; yo1 = po.y + xc[3].y;
    }
    const float f0 = sigm(yf0), f1 = sigm(yf1);
    const float i0 = sigm(yi0), i1 = sigm(yi1);
    const float g0 = tanh_f(yg0), g1 = tanh_f(yg1);
    const float o0 = sigm(yo0), o1 = sigm(yo1);
    cc.x = cc.x * f0 + i0 * g0;
    cc.y = cc.y * f1 + i1 * g1;
    const float h0v = o0 * tanh_f(cc.x);
    const float h1v = o1 * tanh_f(cc.y);
    hprev.x = h0v; hprev.y = h1v;

    // h -> fp16 double buffer for next step's B-frags
    {
      _Float16 p0 = (_Float16)h0v, p1 = (_Float16)h1v;
      unsigned hp = (unsigned)__builtin_bit_cast(unsigned short, p0) |
                    ((unsigned)__builtin_bit_cast(unsigned short, p1) << 16);
      *(unsigned*)&hbuf[np][dp >> 3][db][dp & 7] = hp;
    }
#pragma unroll
    for (int g = 0; g < 4; ++g) xc[g] = xn[g];
    __syncthreads();
  }

  // final h_seq row + hT/cT
  *(float2*)&hsp[(size_t)(SS - 1) * 256] = hprev;
  *(float2*)&out[8388608 + (size_t)gdb * 256 + dp] = hprev;
  *(float2*)&out[8404992 + (size_t)gdb * 256 + dp] = cc;
}

// ---------------------------------------------------------------- launch
extern "C" void kernel_launch(void* const* d_in, const int* in_sizes, int n_in,
                              void* d_out, int out_size, void* d_ws, size_t ws_size,
                              hipStream_t stream) {
  const float* x  = (const float*)d_in[0];
  const float* h0 = (const float*)d_in[1];
  const float* c0 = (const float*)d_in[2];
  const float* Wh = (const float*)d_in[3];
  const float* bh = (const float*)d_in[4];
  const float* Wx = (const float*)d_in[5];
  const float* bx = (const float*)d_in[6];
  float* out = (float*)d_out;

  float* xg = (float*)d_ws;   // 32768*1024 floats = 128 MB

  xg_gemm<<<dim3(8192), dim3(256), 0, stream>>>(x, Wx, bx, bh, xg);
  lstm_scan4<<<dim3(16), dim3(512), 0, stream>>>(xg, Wh, h0, c0, out);
}

// Round 5
// 1322.842 us; speedup vs baseline: 2.9911x; 2.9911x over previous
//
#include <hip/hip_runtime.h>

// B=64, S=512, I=256, O=256 fp32 LSTM.
// out = [h_seq (64*512*256)] [hT (64*256)] [cT (64*256)]
//
// Phase A: xg = x @ Wx^T + bx + bh  (fp32 LDS-tiled GEMM, known-good)
// Phase B (MFMA scan, register-budgeted): 64 blocks x 1 batch, 512 threads
//   (8 waves -> 2/SIMD -> HARD cap 256 VGPR+AGPR per wave; round-4 spill
//   post-mortem). Wave w owns rows g*256 + w*32 + i*16 (8 16-row tiles).
//   k<192: A-frags in registers (192 regs, MFMA-only use -> AGPR bank).
//   k in [192,256): fp16 weights in LDS (128 KB), self-swizzled so each
//   lane reads its own 16B frag (dense, conflict-free).
//   h(t) fp16 in LDS (512 B, double-buffered): 8 B-frag reads/wave/step.
//   D[8] f32x4. Scatter y (lanes l15==0) -> ylds[gate][p] b128, barrier,
//   gate phase dense in waves 0-3 (1 c-update/thread), h -> hbuf, barrier.

#define SS 512

typedef _Float16 v8h __attribute__((ext_vector_type(8)));
typedef float vf4 __attribute__((ext_vector_type(4)));

__device__ __forceinline__ float sigm(float x) { return 1.f / (1.f + __expf(-x)); }
__device__ __forceinline__ float tanh_f(float x) {
  float e = __expf(-2.f * fabsf(x));
  float r = (1.f - e) / (1.f + e);
  return copysignf(r, x);
}

// ---------------------------------------------------------------- Phase A
__global__ __launch_bounds__(256) void xg_gemm(
    const float* __restrict__ X, const float* __restrict__ W,
    const float* __restrict__ bx, const float* __restrict__ bh,
    float* __restrict__ out)
{
  __shared__ float As[64][68];
  __shared__ float Bs[64][68];
  const int bm = blockIdx.x >> 4;
  const int bn = blockIdx.x & 15;
  const int tid = threadIdx.x;
  const int tn = tid & 15, tm = tid >> 4;
  const int row0 = bm * 64, col0 = bn * 64;
  float acc[4][4] = {};

  for (int k0 = 0; k0 < 256; k0 += 64) {
#pragma unroll
    for (int i = 0; i < 4; i++) {
      const int m = (tid >> 4) + i * 16;
      const int k = (tid & 15) * 4;
      float4 av = *(const float4*)&X[(size_t)(row0 + m) * 256 + k0 + k];
      *(float4*)&As[m][k] = av;
      float4 wv = *(const float4*)&W[(size_t)(col0 + m) * 256 + k0 + k];
      Bs[k + 0][m] = wv.x; Bs[k + 1][m] = wv.y;
      Bs[k + 2][m] = wv.z; Bs[k + 3][m] = wv.w;
    }
    __syncthreads();
#pragma unroll 8
    for (int kk = 0; kk < 64; kk++) {
      const float a0 = As[tm * 4 + 0][kk];
      const float a1 = As[tm * 4 + 1][kk];
      const float a2 = As[tm * 4 + 2][kk];
      const float a3 = As[tm * 4 + 3][kk];
      const float4 bv = *(const float4*)&Bs[kk][tn * 4];
      acc[0][0] = fmaf(a0, bv.x, acc[0][0]); acc[0][1] = fmaf(a0, bv.y, acc[0][1]);
      acc[0][2] = fmaf(a0, bv.z, acc[0][2]); acc[0][3] = fmaf(a0, bv.w, acc[0][3]);
      acc[1][0] = fmaf(a1, bv.x, acc[1][0]); acc[1][1] = fmaf(a1, bv.y, acc[1][1]);
      acc[1][2] = fmaf(a1, bv.z, acc[1][2]); acc[1][3] = fmaf(a1, bv.w, acc[1][3]);
      acc[2][0] = fmaf(a2, bv.x, acc[2][0]); acc[2][1] = fmaf(a2, bv.y, acc[2][1]);
      acc[2][2] = fmaf(a2, bv.z, acc[2][2]); acc[2][3] = fmaf(a2, bv.w, acc[2][3]);
      acc[3][0] = fmaf(a3, bv.x, acc[3][0]); acc[3][1] = fmaf(a3, bv.y, acc[3][1]);
      acc[3][2] = fmaf(a3, bv.z, acc[3][2]); acc[3][3] = fmaf(a3, bv.w, acc[3][3]);
    }
    __syncthreads();
  }

  float bias[4];
#pragma unroll
  for (int j = 0; j < 4; j++) {
    const int col = col0 + tn * 4 + j;
    bias[j] = bx[col] + bh[col];
  }
#pragma unroll
  for (int i = 0; i < 4; i++) {
    float4 o4;
    o4.x = acc[i][0] + bias[0]; o4.y = acc[i][1] + bias[1];
    o4.z = acc[i][2] + bias[2]; o4.w = acc[i][3] + bias[3];
    *(float4*)&out[(size_t)(row0 + tm * 4 + i) * 1024 + col0 + tn * 4] = o4;
  }
}

// ---------------------------------------------------------------- Phase B
__global__ __launch_bounds__(512) void lstm_scan5(
    const float* __restrict__ xg,   // [64][512][1024]
    const float* __restrict__ Wh,   // [1024][256]  row = g*256+p, col = k
    const float* __restrict__ h0,   // [64][256]
    const float* __restrict__ c0,   // [64][256]
    float* __restrict__ out)
{
  // tail weights, self-swizzled: [(w*8+j)*2+kfi][lane][8 halves] = 128 KB
  __shared__ __align__(16) _Float16 wtail[8 * 8 * 2 * 64 * 8];
  __shared__ __align__(16) _Float16 hbuf[2][256];   // 1 KB, double buffer
  __shared__ __align__(16) float ylds[4][256];      // 4 KB

  const int tid  = threadIdx.x;
  const int b    = blockIdx.x;
  const int w    = tid >> 6;
  const int lane = tid & 63;
  const int q    = lane >> 4;
  const int l15  = lane & 15;

  // ---- A-frags (k<192) into regs; tail (k in [192,256)) into LDS
  v8h A[8][6];
#pragma unroll
  for (int j = 0; j < 8; ++j) {
    const int g = j >> 1, i = j & 1;
    const float* rp = Wh + (size_t)(g * 256 + w * 32 + i * 16 + l15) * 256 + q * 8;
#pragma unroll
    for (int kf = 0; kf < 6; ++kf) {
      float4 lo = *(const float4*)(rp + kf * 32);
      float4 hi = *(const float4*)(rp + kf * 32 + 4);
      v8h a;
      a[0] = (_Float16)lo.x; a[1] = (_Float16)lo.y;
      a[2] = (_Float16)lo.z; a[3] = (_Float16)lo.w;
      a[4] = (_Float16)hi.x; a[5] = (_Float16)hi.y;
      a[6] = (_Float16)hi.z; a[7] = (_Float16)hi.w;
      A[j][kf] = a;
    }
#pragma unroll
    for (int kfi = 0; kfi < 2; ++kfi) {
      float4 lo = *(const float4*)(rp + 192 + kfi * 32);
      float4 hi = *(const float4*)(rp + 192 + kfi * 32 + 4);
      _Float16* dst = &wtail[((((w * 8 + j) * 2) + kfi) * 64 + lane) * 8];
      dst[0] = (_Float16)lo.x; dst[1] = (_Float16)lo.y;
      dst[2] = (_Float16)lo.z; dst[3] = (_Float16)lo.w;
      dst[4] = (_Float16)hi.x; dst[5] = (_Float16)hi.y;
      dst[6] = (_Float16)hi.z; dst[7] = (_Float16)hi.w;
    }
  }

  if (tid < 256) hbuf[0][tid] = (_Float16)h0[(size_t)b * 256 + tid];
  float c = (tid < 256) ? c0[(size_t)b * 256 + tid] : 0.f;
  __syncthreads();

  const float* xb = xg + (size_t)b * SS * 1024;
  float* hs = out + (size_t)b * SS * 256;
  float hprev = 0.f;

  for (int t = 0; t < SS; ++t) {
    const int par = t & 1;

    float xc0 = 0.f, xc1 = 0.f, xc2 = 0.f, xc3 = 0.f;
    if (tid < 256) {
      if (t > 0) hs[(size_t)(t - 1) * 256 + tid] = hprev;  // deferred store
      const float* xp = xb + (size_t)t * 1024 + tid;
      xc0 = xp[0]; xc1 = xp[256]; xc2 = xp[512]; xc3 = xp[768];
    }

    vf4 D[8];
#pragma unroll
    for (int j = 0; j < 8; ++j) { vf4 z = {0.f, 0.f, 0.f, 0.f}; D[j] = z; }

    // k < 192: A from regs (AGPR), B = h broadcast from LDS
#pragma unroll
    for (int kf = 0; kf < 6; ++kf) {
      v8h Bf = *(const v8h*)&hbuf[par][kf * 32 + q * 8];
#pragma unroll
      for (int j = 0; j < 8; ++j)
        D[j] = __builtin_amdgcn_mfma_f32_16x16x32_f16(A[j][kf], Bf, D[j], 0, 0, 0);
    }
    // k in [192,256): A streamed from LDS
#pragma unroll
    for (int kfi = 0; kfi < 2; ++kfi) {
      v8h Bf = *(const v8h*)&hbuf[par][(6 + kfi) * 32 + q * 8];
#pragma unroll
      for (int j = 0; j < 8; ++j) {
        v8h wt = *(const v8h*)&wtail[((((w * 8 + j) * 2) + kfi) * 64 + lane) * 8];
        D[j] = __builtin_amdgcn_mfma_f32_16x16x32_f16(wt, Bf, D[j], 0, 0, 0);
      }
    }

    // scatter y: D rows (q*4+r) of tile (g,i) -> ylds[g][p], col 0 lanes only
    if (l15 == 0) {
#pragma unroll
      for (int j = 0; j < 8; ++j) {
        const int g = j >> 1, i = j & 1;
        *(vf4*)&ylds[g][w * 32 + i * 16 + q * 4] = D[j];
      }
    }
    __syncthreads();

    // dense gate phase: waves 0-3, one c-update per thread (p = tid)
    if (tid < 256) {
      const float y0 = ylds[0][tid] + xc0;   // f
      const float y1 = ylds[1][tid] + xc1;   // i
      const float y2 = ylds[2][tid] + xc2;   // g
      const float y3 = ylds[3][tid] + xc3;   // o
      const float fg = sigm(y0);
      const float ig = sigm(y1);
      const float gt = tanh_f(y2);
      const float og = sigm(y3);
      c = c * fg + ig * gt;
      const float h = og * tanh_f(c);
      hprev = h;
      hbuf[par ^ 1][tid] = (_Float16)h;
    }
    __syncthreads();
  }

  if (tid < 256) {
    hs[(size_t)(SS - 1) * 256 + tid] = hprev;
    out[8388608 + (size_t)b * 256 + tid] = hprev;   // hT
    out[8404992 + (size_t)b * 256 + tid] = c;       // cT
  }
}

// ---------------------------------------------------------------- launch
extern "C" void kernel_launch(void* const* d_in, const int* in_sizes, int n_in,
                              void* d_out, int out_size, void* d_ws, size_t ws_size,
                              hipStream_t stream) {
  const float* x  = (const float*)d_in[0];
  const float* h0 = (const float*)d_in[1];
  const float* c0 = (const float*)d_in[2];
  const float* Wh = (const float*)d_in[3];
  const float* bh = (const float*)d_in[4];
  const float* Wx = (const float*)d_in[5];
  const float* bx = (const float*)d_in[6];
  float* out = (float*)d_out;

  float* xg = (float*)d_ws;   // 32768*1024 floats = 128 MB

  xg_gemm<<<dim3(8192), dim3(256), 0, stream>>>(x, Wx, bx, bh, xg);
  lstm_scan5<<<dim3(64), dim3(512), 0, stream>>>(xg, Wh, h0, c0, out);
}